// Round 4
// baseline (1630.311 us; speedup 1.0000x reference)
//
#include <hip/hip_runtime.h>
#include <math.h>

#define BB    32
#define CCH   64
#define DIMN  1024
#define NCLS  10

typedef __attribute__((ext_vector_type(8))) short bf16x8;
typedef __attribute__((ext_vector_type(4))) float f32x4;
typedef __attribute__((ext_vector_type(4))) unsigned short us4;

#define MFMA16(a, b, c) __builtin_amdgcn_mfma_f32_16x16x32_bf16(a, b, c, 0, 0, 0)

__device__ __forceinline__ unsigned short f2bf(float x) {
  unsigned u = __float_as_uint(x);
  unsigned r = u + 0x7fffu + ((u >> 16) & 1u);   // round-to-nearest-even
  return (unsigned short)(r >> 16);
}
__device__ __forceinline__ float bf2f(unsigned short h) {
  return __uint_as_float(((unsigned)h) << 16);
}
// x == h + m + l to ~2^-26 relative
__device__ __forceinline__ void split3(float x, unsigned short& h,
                                       unsigned short& m, unsigned short& l) {
  h = f2bf(x); float hf = bf2f(h);
  float r = x - hf;
  m = f2bf(r); float mf = bf2f(m);
  l = f2bf(r - mf);
}
__device__ __forceinline__ bf16x8 ld8(const unsigned short* p) {
  union { bf16x8 v; us4 h[2]; } u;
  u.h[0] = *(const us4*)(p);
  u.h[1] = *(const us4*)(p + 4);
  return u.v;
}
__device__ __forceinline__ bf16x8 ldg8(const unsigned short* p) {
  return *(const bf16x8*)p;      // 16B-aligned global load
}

// ---------------------------------------------------------------------------
// 1) transpose: image (B,C,DIM) -> X (B,DIM,C)
// ---------------------------------------------------------------------------
__global__ __launch_bounds__(256) void k_transpose(const float* __restrict__ img,
                                                   float* __restrict__ X) {
  __shared__ float tile[64][65];
  const int b  = blockIdx.y;
  const int n0 = blockIdx.x * 64;
  const int tx = threadIdx.x & 63;
  const int ty = threadIdx.x >> 6;
  const float* src = img + (size_t)b * CCH * DIMN;
  #pragma unroll
  for (int c = ty; c < 64; c += 4)
    tile[c][tx] = src[(size_t)c * DIMN + n0 + tx];
  __syncthreads();
  float* dst = X + (size_t)b * DIMN * CCH;
  #pragma unroll
  for (int nn = ty; nn < 64; nn += 4)
    dst[(size_t)(n0 + nn) * CCH + tx] = tile[tx][nn];
}

// ---------------------------------------------------------------------------
// 2) QKV + per-layer pre-split: Q fp32; K 3-term bf16 [t][c]; V 3-term bf16
//    TRANSPOSED [c][t] (per batch) via in-block LDS transpose.
//    Splits computed ONCE here instead of 16x redundantly in attn.
// ---------------------------------------------------------------------------
__global__ __launch_bounds__(256) void k_qkv_split(
    const float* __restrict__ X,
    const float* __restrict__ WQ, const float* __restrict__ WK,
    const float* __restrict__ WV,
    float* __restrict__ Q,
    unsigned short* __restrict__ Kh, unsigned short* __restrict__ Km,
    unsigned short* __restrict__ Kl,
    unsigned short* __restrict__ VhT, unsigned short* __restrict__ VmT,
    unsigned short* __restrict__ VlT) {
  __shared__ float xs[16][64];
  __shared__ unsigned short vs[3][16][64];
  const int c  = threadIdx.x & 63;
  const int tg = threadIdx.x >> 6;
  const size_t t0 = (size_t)blockIdx.x * 16;
  #pragma unroll
  for (int r = tg; r < 16; r += 4)
    xs[r][c] = X[(t0 + r) * 64 + c];
  __syncthreads();
  float qa[4] = {0.f,0.f,0.f,0.f};
  float ka[4] = {0.f,0.f,0.f,0.f};
  float va[4] = {0.f,0.f,0.f,0.f};
  for (int j = 0; j < 64; ++j) {
    const float wq = WQ[j * 64 + c];
    const float wk = WK[j * 64 + c];
    const float wv = WV[j * 64 + c];
    #pragma unroll
    for (int r = 0; r < 4; ++r) {
      const float x = xs[tg * 4 + r][j];
      qa[r] = fmaf(x, wq, qa[r]);
      ka[r] = fmaf(x, wk, ka[r]);
      va[r] = fmaf(x, wv, va[r]);
    }
  }
  #pragma unroll
  for (int r = 0; r < 4; ++r) {
    const int t = tg * 4 + r;
    const size_t idx = (t0 + t) * 64 + c;
    Q[idx] = qa[r];
    unsigned short h, m, l;
    split3(ka[r], h, m, l);
    Kh[idx] = h; Km[idx] = m; Kl[idx] = l;
    split3(va[r], h, m, l);
    vs[0][t][c] = h; vs[1][t][c] = m; vs[2][t][c] = l;
  }
  __syncthreads();
  // transposed V writes: thread -> (c-row = tid>>2, 4 tokens at part*4)
  {
    const int row  = threadIdx.x >> 2;
    const int part = threadIdx.x & 3;
    const size_t bofs = (t0 >> 10) * ((size_t)DIMN * 64);   // batch * 65536
    const size_t tl   = (t0 & 1023) + part * 4;
    unsigned short* dst[3] = {VhT, VmT, VlT};
    #pragma unroll
    for (int term = 0; term < 3; ++term) {
      us4 pk;
      #pragma unroll
      for (int i = 0; i < 4; ++i) pk[i] = vs[term][part * 4 + i][row];
      *(us4*)&dst[term][bofs + (size_t)row * DIMN + tl] = pk;
    }
  }
}

// ---------------------------------------------------------------------------
// 3) MFMA flash attention, B-fragments DIRECT FROM GLOBAL (pre-split K/V).
//    No K/V LDS staging, no split3 in the loop, ZERO barriers in the K-loop
//    (P LDS round-trip is wave-local). LDS = P only (9.2 KB).
//    Same split values + same MFMA order as round 3 => bit-identical output.
//    Last layer also emits per-token channel-means (fused head stage 1).
// ---------------------------------------------------------------------------
__global__ __launch_bounds__(256) void k_attn_g(
    const float* __restrict__ Qg,
    const unsigned short* __restrict__ Kh, const unsigned short* __restrict__ Km,
    const unsigned short* __restrict__ Kl,
    const unsigned short* __restrict__ VhT, const unsigned short* __restrict__ VmT,
    const unsigned short* __restrict__ VlT,
    float* __restrict__ X, float* __restrict__ meanout) {
  __shared__ __align__(16) float Pb[64 * 36];

  const int tid  = threadIdx.x;
  const int w    = tid >> 6;
  const int lane = tid & 63;
  const int ln   = lane & 15;
  const int q    = lane >> 4;
  const int b    = blockIdx.y;
  const int i0   = blockIdx.x * 64;
  const size_t base  = (size_t)b * (DIMN * 64);   // fp32 & split-array stride
  const float scale = 0.03125f;

  // ---- Q fragments: 3-term split, 2 k-chunks (once per block) --------------
  bf16x8 qh[2], qm[2], ql[2];
  {
    const int mrow = i0 + 16 * w + ln;
    const float* qp = Qg + base + (size_t)mrow * 64 + 8 * q;
    #pragma unroll
    for (int s = 0; s < 2; ++s) {
      const float4 x0 = ((const float4*)(qp + 32 * s))[0];
      const float4 x1 = ((const float4*)(qp + 32 * s))[1];
      const float xv[8] = {x0.x, x0.y, x0.z, x0.w, x1.x, x1.y, x1.z, x1.w};
      union { bf16x8 v; unsigned short e[8]; } uh, um, ul;
      #pragma unroll
      for (int j = 0; j < 8; ++j) {
        unsigned short h, m, l;
        split3(xv[j], h, m, l);
        uh.e[j] = h; um.e[j] = m; ul.e[j] = l;
      }
      qh[s] = uh.v; qm[s] = um.v; ql[s] = ul.v;
    }
  }

  f32x4 O[4];
  #pragma unroll
  for (int ct = 0; ct < 4; ++ct) O[ct] = (f32x4){0.f, 0.f, 0.f, 0.f};
  float m_run[4] = {-INFINITY, -INFINITY, -INFINITY, -INFINITY};
  float l_run[4] = {0.f, 0.f, 0.f, 0.f};

  for (int kt = 0; kt < 32; ++kt) {
    // ---- S strip = Q . K^T, 6-product compensated, K frags from global -----
    f32x4 sacc[2];
    #pragma unroll
    for (int ct = 0; ct < 2; ++ct) {
      f32x4 a = (f32x4){0.f, 0.f, 0.f, 0.f};
      #pragma unroll
      for (int s = 0; s < 2; ++s) {
        const size_t ko = base + (size_t)(kt * 32 + 16 * ct + ln) * 64 + 32 * s + 8 * q;
        const bf16x8 bh = ldg8(&Kh[ko]);
        const bf16x8 bm = ldg8(&Km[ko]);
        const bf16x8 bl = ldg8(&Kl[ko]);
        a = MFMA16(ql[s], bh, a);
        a = MFMA16(qh[s], bl, a);
        a = MFMA16(qm[s], bm, a);
        a = MFMA16(qm[s], bh, a);
        a = MFMA16(qh[s], bm, a);
        a = MFMA16(qh[s], bh, a);
      }
      sacc[ct] = a;
    }

    // ---- wave-local online softmax -----------------------------------------
    float rmax[4];
    #pragma unroll
    for (int r = 0; r < 4; ++r)
      rmax[r] = fmaxf(sacc[0][r], sacc[1][r]);
    #pragma unroll
    for (int mk = 1; mk <= 8; mk <<= 1) {
      #pragma unroll
      for (int r = 0; r < 4; ++r)
        rmax[r] = fmaxf(rmax[r], __shfl_xor(rmax[r], mk, 64));
    }
    float alpha[4], rsum[4];
    #pragma unroll
    for (int r = 0; r < 4; ++r) {
      const float mnew = fmaxf(m_run[r], rmax[r] * scale);
      alpha[r] = __expf(m_run[r] - mnew);
      m_run[r] = mnew;
      rsum[r] = 0.f;
    }
    #pragma unroll
    for (int ct = 0; ct < 2; ++ct) {
      #pragma unroll
      for (int r = 0; r < 4; ++r) {
        const float pv = __expf(sacc[ct][r] * scale - m_run[r]);
        rsum[r] += pv;
        Pb[(16 * w + 4 * q + r) * 36 + ln + 16 * ct] = pv;   // fp32, wave-local
      }
    }
    #pragma unroll
    for (int mk = 1; mk <= 8; mk <<= 1) {
      #pragma unroll
      for (int r = 0; r < 4; ++r)
        rsum[r] += __shfl_xor(rsum[r], mk, 64);
    }
    #pragma unroll
    for (int r = 0; r < 4; ++r)
      l_run[r] = l_run[r] * alpha[r] + rsum[r];

    #pragma unroll
    for (int ct = 0; ct < 4; ++ct) {
      #pragma unroll
      for (int r = 0; r < 4; ++r) O[ct][r] *= alpha[r];
    }

    // ---- P A-fragment: own rows, fp32 -> 3-term split ----------------------
    bf16x8 ph, pm, pl;
    {
      const float* pp = &Pb[(16 * w + ln) * 36 + 8 * q];
      const float4 p0 = ((const float4*)pp)[0];
      const float4 p1 = ((const float4*)pp)[1];
      const float pvv[8] = {p0.x, p0.y, p0.z, p0.w, p1.x, p1.y, p1.z, p1.w};
      union { bf16x8 v; unsigned short e[8]; } uh, um, ul;
      #pragma unroll
      for (int j = 0; j < 8; ++j) {
        unsigned short h, m, l;
        split3(pvv[j], h, m, l);
        uh.e[j] = h; um.e[j] = m; ul.e[j] = l;
      }
      ph = uh.v; pm = um.v; pl = ul.v;
    }

    // ---- O += P @ V, 6-product, V^T frags from global ----------------------
    #pragma unroll
    for (int ct = 0; ct < 4; ++ct) {
      const size_t vo = base + (size_t)(16 * ct + ln) * DIMN + kt * 32 + 8 * q;
      const bf16x8 vvh = ldg8(&VhT[vo]);
      const bf16x8 vvm = ldg8(&VmT[vo]);
      const bf16x8 vvl = ldg8(&VlT[vo]);
      O[ct] = MFMA16(ph, vvh, O[ct]);
      O[ct] = MFMA16(ph, vvm, O[ct]);
      O[ct] = MFMA16(pm, vvh, O[ct]);
      O[ct] = MFMA16(pm, vvm, O[ct]);
      O[ct] = MFMA16(ph, vvl, O[ct]);
      O[ct] = MFMA16(pl, vvh, O[ct]);
    }
  }

  // ---- epilogue: X += O/l; optional fused channel-mean ---------------------
  float linv[4];
  #pragma unroll
  for (int r = 0; r < 4; ++r) linv[r] = 1.0f / l_run[r];
  #pragma unroll
  for (int r = 0; r < 4; ++r) {
    const int row = i0 + 16 * w + 4 * q + r;
    float srow = 0.f;
    #pragma unroll
    for (int ct = 0; ct < 4; ++ct) {
      float* xp = X + base + (size_t)row * 64 + ln + 16 * ct;
      const float nv = *xp + O[ct][r] * linv[r];
      *xp = nv;
      srow += nv;
    }
    if (meanout) {
      #pragma unroll
      for (int mk = 1; mk <= 8; mk <<= 1)
        srow += __shfl_xor(srow, mk, 64);
      if (ln == 0) meanout[(size_t)b * DIMN + row] = srow * (1.0f / 64.0f);
    }
  }
}

// ---------------------------------------------------------------------------
// 4) head stage 2: pred[b,k] = meanv[b,:] . last_W[k,:] + last_b[k]
// ---------------------------------------------------------------------------
__global__ __launch_bounds__(256) void k_head2(
    const float* __restrict__ meanv, const float* __restrict__ lW,
    const float* __restrict__ lb, float* __restrict__ out) {
  __shared__ float red[256];
  const int b   = blockIdx.x;
  const int tid = threadIdx.x;
  float acc[NCLS];
  #pragma unroll
  for (int k = 0; k < NCLS; ++k) acc[k] = 0.f;
  for (int n = tid; n < DIMN; n += 256) {
    const float m = meanv[(size_t)b * DIMN + n];
    #pragma unroll
    for (int k = 0; k < NCLS; ++k)
      acc[k] = fmaf(m, lW[k * DIMN + n], acc[k]);
  }
  for (int k = 0; k < NCLS; ++k) {
    red[tid] = acc[k];
    __syncthreads();
    for (int s = 128; s > 0; s >>= 1) {
      if (tid < s) red[tid] += red[tid + s];
      __syncthreads();
    }
    if (tid == 0) out[b * NCLS + k] = red[0] + lb[k];
    __syncthreads();
  }
}

// ===========================================================================
// FALLBACK PATH (round-3 kernels, ws < 43 MB): proven absmax 0.0
// ===========================================================================
__global__ __launch_bounds__(256) void k_qkv(
    const float* __restrict__ X,
    const float* __restrict__ WQ, const float* __restrict__ WK,
    const float* __restrict__ WV,
    float* __restrict__ Q, float* __restrict__ K, float* __restrict__ V) {
  __shared__ float xs[16][64];
  const int c  = threadIdx.x & 63;
  const int tg = threadIdx.x >> 6;
  const size_t t0 = (size_t)blockIdx.x * 16;
  #pragma unroll
  for (int r = tg; r < 16; r += 4)
    xs[r][c] = X[(t0 + r) * 64 + c];
  __syncthreads();
  float qa[4] = {0.f,0.f,0.f,0.f};
  float ka[4] = {0.f,0.f,0.f,0.f};
  float va[4] = {0.f,0.f,0.f,0.f};
  for (int j = 0; j < 64; ++j) {
    const float wq = WQ[j * 64 + c];
    const float wk = WK[j * 64 + c];
    const float wv = WV[j * 64 + c];
    #pragma unroll
    for (int r = 0; r < 4; ++r) {
      const float x = xs[tg * 4 + r][j];
      qa[r] = fmaf(x, wq, qa[r]);
      ka[r] = fmaf(x, wk, ka[r]);
      va[r] = fmaf(x, wv, va[r]);
    }
  }
  #pragma unroll
  for (int r = 0; r < 4; ++r) {
    const size_t idx = (t0 + tg * 4 + r) * 64 + c;
    Q[idx] = qa[r]; K[idx] = ka[r]; V[idx] = va[r];
  }
}

__global__ __launch_bounds__(256) void k_attn_mfma(
    const float* __restrict__ Qg, const float* __restrict__ Kg,
    const float* __restrict__ Vg, float* __restrict__ X) {
  __shared__ __align__(16) unsigned short Kh[32 * 72];
  __shared__ __align__(16) unsigned short Km[32 * 72];
  __shared__ __align__(16) unsigned short Kl[32 * 72];
  __shared__ __align__(16) unsigned short Vh[64 * 40];
  __shared__ __align__(16) unsigned short Vm[64 * 40];
  __shared__ __align__(16) unsigned short Vl[64 * 40];
  __shared__ __align__(16) float Pb[64 * 36];

  const int tid  = threadIdx.x;
  const int w    = tid >> 6;
  const int lane = tid & 63;
  const int ln   = lane & 15;
  const int q    = lane >> 4;
  const int b    = blockIdx.y;
  const int i0   = blockIdx.x * 64;
  const size_t base = (size_t)b * (DIMN * 64);
  const float scale = 0.03125f;

  const float* Kbase = Kg + base;
  const float* Vbase = Vg + base;

  bf16x8 qh[2], qm[2], ql[2];
  {
    const int mrow = i0 + 16 * w + ln;
    const float* qp = Qg + base + (size_t)mrow * 64 + 8 * q;
    #pragma unroll
    for (int s = 0; s < 2; ++s) {
      const float4 x0 = ((const float4*)(qp + 32 * s))[0];
      const float4 x1 = ((const float4*)(qp + 32 * s))[1];
      const float xv[8] = {x0.x, x0.y, x0.z, x0.w, x1.x, x1.y, x1.z, x1.w};
      union { bf16x8 v; unsigned short e[8]; } uh, um, ul;
      #pragma unroll
      for (int j = 0; j < 8; ++j) {
        unsigned short h, m, l;
        split3(xv[j], h, m, l);
        uh.e[j] = h; um.e[j] = m; ul.e[j] = l;
      }
      qh[s] = uh.v; qm[s] = um.v; ql[s] = ul.v;
    }
  }

  f32x4 O[4];
  #pragma unroll
  for (int ct = 0; ct < 4; ++ct) O[ct] = (f32x4){0.f, 0.f, 0.f, 0.f};
  float m_run[4] = {-INFINITY, -INFINITY, -INFINITY, -INFINITY};
  float l_run[4] = {0.f, 0.f, 0.f, 0.f};

  for (int kt = 0; kt < 32; ++kt) {
    __syncthreads();
    {
      const int j  = tid >> 3;
      const int dq = tid & 7;
      const float* kp = Kbase + (size_t)(kt * 32 + j) * 64 + 8 * dq;
      const float4 a0 = ((const float4*)kp)[0];
      const float4 a1 = ((const float4*)kp)[1];
      const float xv[8] = {a0.x, a0.y, a0.z, a0.w, a1.x, a1.y, a1.z, a1.w};
      const int o = j * 72 + 8 * dq;
      us4 hh[2], mm[2], llv[2];
      #pragma unroll
      for (int e = 0; e < 8; ++e) {
        unsigned short h, m, l;
        split3(xv[e], h, m, l);
        hh[e >> 2][e & 3] = h; mm[e >> 2][e & 3] = m; llv[e >> 2][e & 3] = l;
      }
      *(us4*)&Kh[o] = hh[0];  *(us4*)&Kh[o + 4] = hh[1];
      *(us4*)&Km[o] = mm[0];  *(us4*)&Km[o + 4] = mm[1];
      *(us4*)&Kl[o] = llv[0]; *(us4*)&Kl[o + 4] = llv[1];
    }
    {
      const int jp = tid >> 4;
      const int cq = tid & 15;
      const float* vp = Vbase + (size_t)(kt * 32 + 2 * jp) * 64 + 4 * cq;
      const float4 a = *(const float4*)vp;
      const float4 bb = *(const float4*)(vp + 64);
      const float av[4] = {a.x, a.y, a.z, a.w};
      const float bv[4] = {bb.x, bb.y, bb.z, bb.w};
      #pragma unroll
      for (int e = 0; e < 4; ++e) {
        const int c = 4 * cq + e;
        unsigned short h1, m1, l1, h2, m2, l2;
        split3(av[e], h1, m1, l1);
        split3(bv[e], h2, m2, l2);
        *(unsigned int*)&Vh[c * 40 + 2 * jp] = (unsigned)h1 | ((unsigned)h2 << 16);
        *(unsigned int*)&Vm[c * 40 + 2 * jp] = (unsigned)m1 | ((unsigned)m2 << 16);
        *(unsigned int*)&Vl[c * 40 + 2 * jp] = (unsigned)l1 | ((unsigned)l2 << 16);
      }
    }
    __syncthreads();

    f32x4 sacc[2];
    #pragma unroll
    for (int ct = 0; ct < 2; ++ct) {
      f32x4 a = (f32x4){0.f, 0.f, 0.f, 0.f};
      #pragma unroll
      for (int s = 0; s < 2; ++s) {
        const int ko = (16 * ct + ln) * 72 + 32 * s + 8 * q;
        const bf16x8 bh = ld8(&Kh[ko]);
        const bf16x8 bm = ld8(&Km[ko]);
        const bf16x8 bl = ld8(&Kl[ko]);
        a = MFMA16(ql[s], bh, a);
        a = MFMA16(qh[s], bl, a);
        a = MFMA16(qm[s], bm, a);
        a = MFMA16(qm[s], bh, a);
        a = MFMA16(qh[s], bm, a);
        a = MFMA16(qh[s], bh, a);
      }
      sacc[ct] = a;
    }

    float rmax[4];
    #pragma unroll
    for (int r = 0; r < 4; ++r)
      rmax[r] = fmaxf(sacc[0][r], sacc[1][r]);
    #pragma unroll
    for (int mk = 1; mk <= 8; mk <<= 1) {
      #pragma unroll
      for (int r = 0; r < 4; ++r)
        rmax[r] = fmaxf(rmax[r], __shfl_xor(rmax[r], mk, 64));
    }
    float alpha[4], rsum[4];
    #pragma unroll
    for (int r = 0; r < 4; ++r) {
      const float mnew = fmaxf(m_run[r], rmax[r] * scale);
      alpha[r] = __expf(m_run[r] - mnew);
      m_run[r] = mnew;
      rsum[r] = 0.f;
    }
    #pragma unroll
    for (int ct = 0; ct < 2; ++ct) {
      #pragma unroll
      for (int r = 0; r < 4; ++r) {
        const float pv = __expf(sacc[ct][r] * scale - m_run[r]);
        rsum[r] += pv;
        Pb[(16 * w + 4 * q + r) * 36 + ln + 16 * ct] = pv;
      }
    }
    #pragma unroll
    for (int mk = 1; mk <= 8; mk <<= 1) {
      #pragma unroll
      for (int r = 0; r < 4; ++r)
        rsum[r] += __shfl_xor(rsum[r], mk, 64);
    }
    #pragma unroll
    for (int r = 0; r < 4; ++r)
      l_run[r] = l_run[r] * alpha[r] + rsum[r];

    #pragma unroll
    for (int ct = 0; ct < 4; ++ct) {
      #pragma unroll
      for (int r = 0; r < 4; ++r) O[ct][r] *= alpha[r];
    }

    bf16x8 ph, pm, pl;
    {
      const float* pp = &Pb[(16 * w + ln) * 36 + 8 * q];
      const float4 p0 = ((const float4*)pp)[0];
      const float4 p1 = ((const float4*)pp)[1];
      const float pvv[8] = {p0.x, p0.y, p0.z, p0.w, p1.x, p1.y, p1.z, p1.w};
      union { bf16x8 v; unsigned short e[8]; } uh, um, ul;
      #pragma unroll
      for (int j = 0; j < 8; ++j) {
        unsigned short h, m, l;
        split3(pvv[j], h, m, l);
        uh.e[j] = h; um.e[j] = m; ul.e[j] = l;
      }
      ph = uh.v; pm = um.v; pl = ul.v;
    }

    #pragma unroll
    for (int ct = 0; ct < 4; ++ct) {
      const int vo = (16 * ct + ln) * 40 + 8 * q;
      const bf16x8 vvh = ld8(&Vh[vo]);
      const bf16x8 vvm = ld8(&Vm[vo]);
      const bf16x8 vvl = ld8(&Vl[vo]);
      O[ct] = MFMA16(ph, vvh, O[ct]);
      O[ct] = MFMA16(ph, vvm, O[ct]);
      O[ct] = MFMA16(pm, vvh, O[ct]);
      O[ct] = MFMA16(pm, vvm, O[ct]);
      O[ct] = MFMA16(ph, vvl, O[ct]);
      O[ct] = MFMA16(pl, vvh, O[ct]);
    }
  }

  float linv[4];
  #pragma unroll
  for (int r = 0; r < 4; ++r) linv[r] = 1.0f / l_run[r];
  #pragma unroll
  for (int ct = 0; ct < 4; ++ct) {
    #pragma unroll
    for (int r = 0; r < 4; ++r) {
      float* xp = X + base + (size_t)(i0 + 16 * w + 4 * q + r) * 64 + ln + 16 * ct;
      *xp += O[ct][r] * linv[r];
    }
  }
}

__global__ __launch_bounds__(256) void k_head(
    const float* __restrict__ X, const float* __restrict__ lW,
    const float* __restrict__ lb, float* __restrict__ out) {
  __shared__ float meanv[DIMN];
  __shared__ float red[256];
  const int b    = blockIdx.x;
  const int tid  = threadIdx.x;
  const int lane = tid & 63;
  const int w    = tid >> 6;
  const float* Xb = X + (size_t)b * DIMN * 64;
  for (int n = w; n < DIMN; n += 4) {
    float v = Xb[(size_t)n * 64 + lane];
    #pragma unroll
    for (int off = 32; off > 0; off >>= 1)
      v += __shfl_down(v, off, 64);
    if (lane == 0) meanv[n] = v * (1.0f / 64.0f);
  }
  __syncthreads();
  float acc[NCLS];
  #pragma unroll
  for (int k = 0; k < NCLS; ++k) acc[k] = 0.f;
  for (int n = tid; n < DIMN; n += 256) {
    const float m = meanv[n];
    #pragma unroll
    for (int k = 0; k < NCLS; ++k)
      acc[k] = fmaf(m, lW[k * DIMN + n], acc[k]);
  }
  for (int k = 0; k < NCLS; ++k) {
    red[tid] = acc[k];
    __syncthreads();
    for (int s = 128; s > 0; s >>= 1) {
      if (tid < s) red[tid] += red[tid + s];
      __syncthreads();
    }
    if (tid == 0) out[b * NCLS + k] = red[0] + lb[k];
    __syncthreads();
  }
}

// ---------------------------------------------------------------------------
// launch
// ---------------------------------------------------------------------------
extern "C" void kernel_launch(void* const* d_in, const int* in_sizes, int n_in,
                              void* d_out, int out_size, void* d_ws, size_t ws_size,
                              hipStream_t stream) {
  const float* image = (const float*)d_in[0];
  const float* WV    = (const float*)d_in[1];
  const float* WK    = (const float*)d_in[2];
  const float* WQ    = (const float*)d_in[3];
  const float* lW    = (const float*)d_in[4];
  const float* lb    = (const float*)d_in[5];
  float* out = (float*)d_out;

  float* ws = (float*)d_ws;
  const size_t NELEM = (size_t)BB * DIMN * CCH;   // 2,097,152

  const size_t need_fast = 2 * NELEM * sizeof(float)          // X, Q
                         + 6 * NELEM * sizeof(unsigned short) // K/V splits
                         + (size_t)BB * DIMN * sizeof(float); // meanv

  if (ws_size >= need_fast) {
    float* X = ws;
    float* Q = ws + NELEM;
    unsigned short* Kh  = (unsigned short*)(ws + 2 * NELEM);
    unsigned short* Km  = Kh + NELEM;
    unsigned short* Kl  = Kh + 2 * NELEM;
    unsigned short* VhT = Kh + 3 * NELEM;
    unsigned short* VmT = Kh + 4 * NELEM;
    unsigned short* VlT = Kh + 5 * NELEM;
    float* meanv = (float*)(Kh + 6 * NELEM);

    k_transpose<<<dim3(DIMN / 64, BB), 256, 0, stream>>>(image, X);
    for (int layer = 0; layer < 8; ++layer) {
      k_qkv_split<<<(BB * DIMN) / 16, 256, 0, stream>>>(
          X, WQ, WK, WV, Q, Kh, Km, Kl, VhT, VmT, VlT);
      k_attn_g<<<dim3(DIMN / 64, BB), 256, 0, stream>>>(
          Q, Kh, Km, Kl, VhT, VmT, VlT, X, (layer == 7) ? meanv : nullptr);
    }
    k_head2<<<BB, 256, 0, stream>>>(meanv, lW, lb, out);
  } else {
    float* X = ws;
    float* Q = ws + NELEM;
    float* K = ws + 2 * NELEM;
    float* V = ws + 3 * NELEM;
    k_transpose<<<dim3(DIMN / 64, BB), 256, 0, stream>>>(image, X);
    for (int layer = 0; layer < 8; ++layer) {
      k_qkv<<<(BB * DIMN) / 16, 256, 0, stream>>>(X, WQ, WK, WV, Q, K, V);
      k_attn_mfma<<<dim3(DIMN / 64, BB), 256, 0, stream>>>(Q, K, V, X);
    }
    k_head<<<BB, 256, 0, stream>>>(X, lW, lb, out);
  }
}

// Round 5
// 922.238 us; speedup vs baseline: 1.7678x; 1.7678x over previous
//
#include <hip/hip_runtime.h>
#include <math.h>

#define BB    32
#define CCH   64
#define DIMN  1024
#define NCLS  10

typedef __attribute__((ext_vector_type(8))) short bf16x8;
typedef __attribute__((ext_vector_type(4))) float f32x4;
typedef __attribute__((ext_vector_type(4))) unsigned short us4;
typedef __attribute__((ext_vector_type(8))) unsigned short us8;

#define MFMA16(a, b, c) __builtin_amdgcn_mfma_f32_16x16x32_bf16(a, b, c, 0, 0, 0)

__device__ __forceinline__ unsigned short f2bf(float x) {
  unsigned u = __float_as_uint(x);
  unsigned r = u + 0x7fffu + ((u >> 16) & 1u);   // round-to-nearest-even
  return (unsigned short)(r >> 16);
}
__device__ __forceinline__ float bf2f(unsigned short h) {
  return __uint_as_float(((unsigned)h) << 16);
}
// x == h + m + l to ~2^-26 relative
__device__ __forceinline__ void split3(float x, unsigned short& h,
                                       unsigned short& m, unsigned short& l) {
  h = f2bf(x); float hf = bf2f(h);
  float r = x - hf;
  m = f2bf(r); float mf = bf2f(m);
  l = f2bf(r - mf);
}
__device__ __forceinline__ bf16x8 ld16B(const unsigned short* p) {
  union { us8 u; bf16x8 v; } c;
  c.u = *(const us8*)p;           // 16B-aligned -> ds_read_b128
  return c.v;
}

// ---------------------------------------------------------------------------
// 1) transpose: image (B,C,DIM) -> X (B,DIM,C)
// ---------------------------------------------------------------------------
__global__ __launch_bounds__(256) void k_transpose(const float* __restrict__ img,
                                                   float* __restrict__ X) {
  __shared__ float tile[64][65];
  const int b  = blockIdx.y;
  const int n0 = blockIdx.x * 64;
  const int tx = threadIdx.x & 63;
  const int ty = threadIdx.x >> 6;
  const float* src = img + (size_t)b * CCH * DIMN;
  #pragma unroll
  for (int c = ty; c < 64; c += 4)
    tile[c][tx] = src[(size_t)c * DIMN + n0 + tx];
  __syncthreads();
  float* dst = X + (size_t)b * DIMN * CCH;
  #pragma unroll
  for (int nn = ty; nn < 64; nn += 4)
    dst[(size_t)(n0 + nn) * CCH + tx] = tile[tx][nn];
}

// ---------------------------------------------------------------------------
// 2) QKV + per-layer pre-split: Q fp32; K 3-term bf16 [t][c] (tile-contig);
//    V 3-term bf16 TRANSPOSED + TILED: [b][kt][c][32] so a 32-key tile is one
//    4 KB contiguous block (perfectly coalesced staging in attn).
//    Splits computed ONCE per layer (hoisted out of attn: r4's proven win).
// ---------------------------------------------------------------------------
__global__ __launch_bounds__(256) void k_qkv_split(
    const float* __restrict__ X,
    const float* __restrict__ WQ, const float* __restrict__ WK,
    const float* __restrict__ WV,
    float* __restrict__ Q,
    unsigned short* __restrict__ Kh, unsigned short* __restrict__ Km,
    unsigned short* __restrict__ Kl,
    unsigned short* __restrict__ VhT, unsigned short* __restrict__ VmT,
    unsigned short* __restrict__ VlT) {
  __shared__ float xs[16][64];
  __shared__ unsigned short vs[3][16][64];
  const int c  = threadIdx.x & 63;
  const int tg = threadIdx.x >> 6;
  const size_t t0 = (size_t)blockIdx.x * 16;
  #pragma unroll
  for (int r = tg; r < 16; r += 4)
    xs[r][c] = X[(t0 + r) * 64 + c];
  __syncthreads();
  float qa[4] = {0.f,0.f,0.f,0.f};
  float ka[4] = {0.f,0.f,0.f,0.f};
  float va[4] = {0.f,0.f,0.f,0.f};
  for (int j = 0; j < 64; ++j) {
    const float wq = WQ[j * 64 + c];
    const float wk = WK[j * 64 + c];
    const float wv = WV[j * 64 + c];
    #pragma unroll
    for (int r = 0; r < 4; ++r) {
      const float x = xs[tg * 4 + r][j];
      qa[r] = fmaf(x, wq, qa[r]);
      ka[r] = fmaf(x, wk, ka[r]);
      va[r] = fmaf(x, wv, va[r]);
    }
  }
  #pragma unroll
  for (int r = 0; r < 4; ++r) {
    const int t = tg * 4 + r;
    const size_t idx = (t0 + t) * 64 + c;
    Q[idx] = qa[r];
    unsigned short h, m, l;
    split3(ka[r], h, m, l);
    Kh[idx] = h; Km[idx] = m; Kl[idx] = l;
    split3(va[r], h, m, l);
    vs[0][t][c] = h; vs[1][t][c] = m; vs[2][t][c] = l;
  }
  __syncthreads();
  // tiled-transposed V writes: [b][kt][c][32]
  {
    const int row  = threadIdx.x >> 2;        // c: 0..63
    const int part = threadIdx.x & 3;         // 4-token group
    const size_t bofs = (t0 >> 10) * ((size_t)DIMN * 64);   // batch * 65536
    const size_t kt   = (t0 & 1023) >> 5;                   // 32-key tile
    const size_t tin  = (t0 & 31) + part * 4;               // col in tile
    unsigned short* dst[3] = {VhT, VmT, VlT};
    #pragma unroll
    for (int term = 0; term < 3; ++term) {
      us4 pk;
      #pragma unroll
      for (int i = 0; i < 4; ++i) pk[i] = vs[term][part * 4 + i][row];
      *(us4*)&dst[term][bofs + kt * 2048 + (size_t)row * 32 + tin] = pk;
    }
  }
}

// ---------------------------------------------------------------------------
// 3) MFMA flash attention: LDS-staged PRE-SPLIT K/V (pure 16B copies — no
//    split3 in the K-loop). Same split values + same MFMA order as r3/r4
//    => bit-identical output (absmax 0.0 proven for this arithmetic path).
//    Per iter/thread staging: 6 coalesced global 16B loads + 6 ds_write_b128.
//    LDS: K 13.8 + V^T 15.4 + P 9.2 = 38.4 KB -> 4 blocks/CU.
//    Last layer emits per-token channel means (fused head stage 1).
// ---------------------------------------------------------------------------
__global__ __launch_bounds__(256) void k_attn_s(
    const float* __restrict__ Qg,
    const unsigned short* __restrict__ Kh, const unsigned short* __restrict__ Km,
    const unsigned short* __restrict__ Kl,
    const unsigned short* __restrict__ VhT, const unsigned short* __restrict__ VmT,
    const unsigned short* __restrict__ VlT,
    float* __restrict__ X, float* __restrict__ meanout) {
  __shared__ __align__(16) unsigned short Khs[32 * 72];
  __shared__ __align__(16) unsigned short Kms[32 * 72];
  __shared__ __align__(16) unsigned short Kls[32 * 72];
  __shared__ __align__(16) unsigned short Vhs[64 * 40];   // V^T: [c][j]
  __shared__ __align__(16) unsigned short Vms[64 * 40];
  __shared__ __align__(16) unsigned short Vls[64 * 40];
  __shared__ __align__(16) float Pb[64 * 36];

  const int tid  = threadIdx.x;
  const int w    = tid >> 6;
  const int lane = tid & 63;
  const int ln   = lane & 15;
  const int q    = lane >> 4;
  const int b    = blockIdx.y;
  const int i0   = blockIdx.x * 64;
  const size_t base = (size_t)b * (DIMN * 64);
  const float scale = 0.03125f;

  // staging addresses (tile-contiguous: tile kt = 4 KB at bofs + kt*2048)
  const int kj = tid >> 3, kg = tid & 7;      // K LDS dest: row kj, group kg
  const int vc = tid >> 2, vg = tid & 3;      // V LDS dest: row vc, group vg
  const int klo = kj * 72 + kg * 8;
  const int vlo = vc * 40 + vg * 8;

  // ---- Q fragments: 3-term split, 2 k-chunks (once per block) --------------
  bf16x8 qh[2], qm[2], ql[2];
  {
    const int mrow = i0 + 16 * w + ln;
    const float* qp = Qg + base + (size_t)mrow * 64 + 8 * q;
    #pragma unroll
    for (int s = 0; s < 2; ++s) {
      const float4 x0 = ((const float4*)(qp + 32 * s))[0];
      const float4 x1 = ((const float4*)(qp + 32 * s))[1];
      const float xv[8] = {x0.x, x0.y, x0.z, x0.w, x1.x, x1.y, x1.z, x1.w};
      union { bf16x8 v; unsigned short e[8]; } uh, um, ul;
      #pragma unroll
      for (int j = 0; j < 8; ++j) {
        unsigned short h, m, l;
        split3(xv[j], h, m, l);
        uh.e[j] = h; um.e[j] = m; ul.e[j] = l;
      }
      qh[s] = uh.v; qm[s] = um.v; ql[s] = ul.v;
    }
  }

  f32x4 O[4];
  #pragma unroll
  for (int ct = 0; ct < 4; ++ct) O[ct] = (f32x4){0.f, 0.f, 0.f, 0.f};
  float m_run[4] = {-INFINITY, -INFINITY, -INFINITY, -INFINITY};
  float l_run[4] = {0.f, 0.f, 0.f, 0.f};

  for (int kt = 0; kt < 32; ++kt) {
    __syncthreads();   // previous iteration's K/V readers done
    {
      const size_t tof = base + (size_t)kt * 2048 + tid * 8;  // shorts
      const us8 a0 = *(const us8*)&Kh[tof];
      const us8 a1 = *(const us8*)&Km[tof];
      const us8 a2 = *(const us8*)&Kl[tof];
      const us8 b0 = *(const us8*)&VhT[tof];
      const us8 b1 = *(const us8*)&VmT[tof];
      const us8 b2 = *(const us8*)&VlT[tof];
      *(us8*)&Khs[klo] = a0;
      *(us8*)&Kms[klo] = a1;
      *(us8*)&Kls[klo] = a2;
      *(us8*)&Vhs[vlo] = b0;
      *(us8*)&Vms[vlo] = b1;
      *(us8*)&Vls[vlo] = b2;
    }
    __syncthreads();

    // ---- S strip = Q . K^T via 6-product compensated MFMA ------------------
    f32x4 sacc[2];
    #pragma unroll
    for (int ct = 0; ct < 2; ++ct) {
      f32x4 a = (f32x4){0.f, 0.f, 0.f, 0.f};
      #pragma unroll
      for (int s = 0; s < 2; ++s) {
        const int ko = (16 * ct + ln) * 72 + 32 * s + 8 * q;
        const bf16x8 bh = ld16B(&Khs[ko]);
        const bf16x8 bm = ld16B(&Kms[ko]);
        const bf16x8 bl = ld16B(&Kls[ko]);
        a = MFMA16(ql[s], bh, a);
        a = MFMA16(qh[s], bl, a);
        a = MFMA16(qm[s], bm, a);
        a = MFMA16(qm[s], bh, a);
        a = MFMA16(qh[s], bm, a);
        a = MFMA16(qh[s], bh, a);
      }
      sacc[ct] = a;
    }

    // ---- wave-local online softmax -----------------------------------------
    float rmax[4];
    #pragma unroll
    for (int r = 0; r < 4; ++r)
      rmax[r] = fmaxf(sacc[0][r], sacc[1][r]);
    #pragma unroll
    for (int mk = 1; mk <= 8; mk <<= 1) {
      #pragma unroll
      for (int r = 0; r < 4; ++r)
        rmax[r] = fmaxf(rmax[r], __shfl_xor(rmax[r], mk, 64));
    }
    float alpha[4], rsum[4];
    #pragma unroll
    for (int r = 0; r < 4; ++r) {
      const float mnew = fmaxf(m_run[r], rmax[r] * scale);
      alpha[r] = __expf(m_run[r] - mnew);
      m_run[r] = mnew;
      rsum[r] = 0.f;
    }
    #pragma unroll
    for (int ct = 0; ct < 2; ++ct) {
      #pragma unroll
      for (int r = 0; r < 4; ++r) {
        const float pv = __expf(sacc[ct][r] * scale - m_run[r]);
        rsum[r] += pv;
        Pb[(16 * w + 4 * q + r) * 36 + ln + 16 * ct] = pv;   // fp32, wave-local
      }
    }
    #pragma unroll
    for (int mk = 1; mk <= 8; mk <<= 1) {
      #pragma unroll
      for (int r = 0; r < 4; ++r)
        rsum[r] += __shfl_xor(rsum[r], mk, 64);
    }
    #pragma unroll
    for (int r = 0; r < 4; ++r)
      l_run[r] = l_run[r] * alpha[r] + rsum[r];

    #pragma unroll
    for (int ct = 0; ct < 4; ++ct) {
      #pragma unroll
      for (int r = 0; r < 4; ++r) O[ct][r] *= alpha[r];
    }

    // ---- P A-fragment: own rows, fp32 -> 3-term split ----------------------
    bf16x8 ph, pm, pl;
    {
      const float* pp = &Pb[(16 * w + ln) * 36 + 8 * q];
      const float4 p0 = ((const float4*)pp)[0];
      const float4 p1 = ((const float4*)pp)[1];
      const float pvv[8] = {p0.x, p0.y, p0.z, p0.w, p1.x, p1.y, p1.z, p1.w};
      union { bf16x8 v; unsigned short e[8]; } uh, um, ul;
      #pragma unroll
      for (int j = 0; j < 8; ++j) {
        unsigned short h, m, l;
        split3(pvv[j], h, m, l);
        uh.e[j] = h; um.e[j] = m; ul.e[j] = l;
      }
      ph = uh.v; pm = um.v; pl = ul.v;
    }

    // ---- O += P @ V, 6-product ---------------------------------------------
    #pragma unroll
    for (int ct = 0; ct < 4; ++ct) {
      const int vo = (16 * ct + ln) * 40 + 8 * q;
      const bf16x8 vvh = ld16B(&Vhs[vo]);
      const bf16x8 vvm = ld16B(&Vms[vo]);
      const bf16x8 vvl = ld16B(&Vls[vo]);
      O[ct] = MFMA16(ph, vvh, O[ct]);
      O[ct] = MFMA16(ph, vvm, O[ct]);
      O[ct] = MFMA16(pm, vvh, O[ct]);
      O[ct] = MFMA16(pm, vvm, O[ct]);
      O[ct] = MFMA16(ph, vvl, O[ct]);
      O[ct] = MFMA16(pl, vvh, O[ct]);
    }
  }

  // ---- epilogue: X += O/l; optional fused channel-mean ---------------------
  float linv[4];
  #pragma unroll
  for (int r = 0; r < 4; ++r) linv[r] = 1.0f / l_run[r];
  #pragma unroll
  for (int r = 0; r < 4; ++r) {
    const int row = i0 + 16 * w + 4 * q + r;
    float srow = 0.f;
    #pragma unroll
    for (int ct = 0; ct < 4; ++ct) {
      float* xp = X + base + (size_t)row * 64 + ln + 16 * ct;
      const float nv = *xp + O[ct][r] * linv[r];
      *xp = nv;
      srow += nv;
    }
    if (meanout) {
      #pragma unroll
      for (int mk = 1; mk <= 8; mk <<= 1)
        srow += __shfl_xor(srow, mk, 64);
      if (ln == 0) meanout[(size_t)b * DIMN + row] = srow * (1.0f / 64.0f);
    }
  }
}

// ---------------------------------------------------------------------------
// 4) head stage 2: pred[b,k] = meanv[b,:] . last_W[k,:] + last_b[k]
// ---------------------------------------------------------------------------
__global__ __launch_bounds__(256) void k_head2(
    const float* __restrict__ meanv, const float* __restrict__ lW,
    const float* __restrict__ lb, float* __restrict__ out) {
  __shared__ float red[256];
  const int b   = blockIdx.x;
  const int tid = threadIdx.x;
  float acc[NCLS];
  #pragma unroll
  for (int k = 0; k < NCLS; ++k) acc[k] = 0.f;
  for (int n = tid; n < DIMN; n += 256) {
    const float m = meanv[(size_t)b * DIMN + n];
    #pragma unroll
    for (int k = 0; k < NCLS; ++k)
      acc[k] = fmaf(m, lW[k * DIMN + n], acc[k]);
  }
  for (int k = 0; k < NCLS; ++k) {
    red[tid] = acc[k];
    __syncthreads();
    for (int s = 128; s > 0; s >>= 1) {
      if (tid < s) red[tid] += red[tid + s];
      __syncthreads();
    }
    if (tid == 0) out[b * NCLS + k] = red[0] + lb[k];
    __syncthreads();
  }
}

// ===========================================================================
// FALLBACK PATH (round-3 kernels, ws too small): proven absmax 0.0
// ===========================================================================
__global__ __launch_bounds__(256) void k_qkv(
    const float* __restrict__ X,
    const float* __restrict__ WQ, const float* __restrict__ WK,
    const float* __restrict__ WV,
    float* __restrict__ Q, float* __restrict__ K, float* __restrict__ V) {
  __shared__ float xs[16][64];
  const int c  = threadIdx.x & 63;
  const int tg = threadIdx.x >> 6;
  const size_t t0 = (size_t)blockIdx.x * 16;
  #pragma unroll
  for (int r = tg; r < 16; r += 4)
    xs[r][c] = X[(t0 + r) * 64 + c];
  __syncthreads();
  float qa[4] = {0.f,0.f,0.f,0.f};
  float ka[4] = {0.f,0.f,0.f,0.f};
  float va[4] = {0.f,0.f,0.f,0.f};
  for (int j = 0; j < 64; ++j) {
    const float wq = WQ[j * 64 + c];
    const float wk = WK[j * 64 + c];
    const float wv = WV[j * 64 + c];
    #pragma unroll
    for (int r = 0; r < 4; ++r) {
      const float x = xs[tg * 4 + r][j];
      qa[r] = fmaf(x, wq, qa[r]);
      ka[r] = fmaf(x, wk, ka[r]);
      va[r] = fmaf(x, wv, va[r]);
    }
  }
  #pragma unroll
  for (int r = 0; r < 4; ++r) {
    const size_t idx = (t0 + tg * 4 + r) * 64 + c;
    Q[idx] = qa[r]; K[idx] = ka[r]; V[idx] = va[r];
  }
}

__global__ __launch_bounds__(256) void k_attn_mfma(
    const float* __restrict__ Qg, const float* __restrict__ Kg,
    const float* __restrict__ Vg, float* __restrict__ X) {
  __shared__ __align__(16) unsigned short Kh[32 * 72];
  __shared__ __align__(16) unsigned short Km[32 * 72];
  __shared__ __align__(16) unsigned short Kl[32 * 72];
  __shared__ __align__(16) unsigned short Vh[64 * 40];
  __shared__ __align__(16) unsigned short Vm[64 * 40];
  __shared__ __align__(16) unsigned short Vl[64 * 40];
  __shared__ __align__(16) float Pb[64 * 36];

  const int tid  = threadIdx.x;
  const int w    = tid >> 6;
  const int lane = tid & 63;
  const int ln   = lane & 15;
  const int q    = lane >> 4;
  const int b    = blockIdx.y;
  const int i0   = blockIdx.x * 64;
  const size_t base = (size_t)b * (DIMN * 64);
  const float scale = 0.03125f;

  const float* Kbase = Kg + base;
  const float* Vbase = Vg + base;

  bf16x8 qh[2], qm[2], ql[2];
  {
    const int mrow = i0 + 16 * w + ln;
    const float* qp = Qg + base + (size_t)mrow * 64 + 8 * q;
    #pragma unroll
    for (int s = 0; s < 2; ++s) {
      const float4 x0 = ((const float4*)(qp + 32 * s))[0];
      const float4 x1 = ((const float4*)(qp + 32 * s))[1];
      const float xv[8] = {x0.x, x0.y, x0.z, x0.w, x1.x, x1.y, x1.z, x1.w};
      union { bf16x8 v; unsigned short e[8]; } uh, um, ul;
      #pragma unroll
      for (int j = 0; j < 8; ++j) {
        unsigned short h, m, l;
        split3(xv[j], h, m, l);
        uh.e[j] = h; um.e[j] = m; ul.e[j] = l;
      }
      qh[s] = uh.v; qm[s] = um.v; ql[s] = ul.v;
    }
  }

  f32x4 O[4];
  #pragma unroll
  for (int ct = 0; ct < 4; ++ct) O[ct] = (f32x4){0.f, 0.f, 0.f, 0.f};
  float m_run[4] = {-INFINITY, -INFINITY, -INFINITY, -INFINITY};
  float l_run[4] = {0.f, 0.f, 0.f, 0.f};

  for (int kt = 0; kt < 32; ++kt) {
    __syncthreads();
    {
      const int j  = tid >> 3;
      const int dq = tid & 7;
      const float* kp = Kbase + (size_t)(kt * 32 + j) * 64 + 8 * dq;
      const float4 a0 = ((const float4*)kp)[0];
      const float4 a1 = ((const float4*)kp)[1];
      const float xv[8] = {a0.x, a0.y, a0.z, a0.w, a1.x, a1.y, a1.z, a1.w};
      const int o = j * 72 + 8 * dq;
      us4 hh[2], mm[2], llv[2];
      #pragma unroll
      for (int e = 0; e < 8; ++e) {
        unsigned short h, m, l;
        split3(xv[e], h, m, l);
        hh[e >> 2][e & 3] = h; mm[e >> 2][e & 3] = m; llv[e >> 2][e & 3] = l;
      }
      *(us4*)&Kh[o] = hh[0];  *(us4*)&Kh[o + 4] = hh[1];
      *(us4*)&Km[o] = mm[0];  *(us4*)&Km[o + 4] = mm[1];
      *(us4*)&Kl[o] = llv[0]; *(us4*)&Kl[o + 4] = llv[1];
    }
    {
      const int jp = tid >> 4;
      const int cq = tid & 15;
      const float* vp = Vbase + (size_t)(kt * 32 + 2 * jp) * 64 + 4 * cq;
      const float4 a = *(const float4*)vp;
      const float4 bb = *(const float4*)(vp + 64);
      const float av[4] = {a.x, a.y, a.z, a.w};
      const float bv[4] = {bb.x, bb.y, bb.z, bb.w};
      #pragma unroll
      for (int e = 0; e < 4; ++e) {
        const int c = 4 * cq + e;
        unsigned short h1, m1, l1, h2, m2, l2;
        split3(av[e], h1, m1, l1);
        split3(bv[e], h2, m2, l2);
        *(unsigned int*)&Vh[c * 40 + 2 * jp] = (unsigned)h1 | ((unsigned)h2 << 16);
        *(unsigned int*)&Vm[c * 40 + 2 * jp] = (unsigned)m1 | ((unsigned)m2 << 16);
        *(unsigned int*)&Vl[c * 40 + 2 * jp] = (unsigned)l1 | ((unsigned)l2 << 16);
      }
    }
    __syncthreads();

    f32x4 sacc[2];
    #pragma unroll
    for (int ct = 0; ct < 2; ++ct) {
      f32x4 a = (f32x4){0.f, 0.f, 0.f, 0.f};
      #pragma unroll
      for (int s = 0; s < 2; ++s) {
        const int ko = (16 * ct + ln) * 72 + 32 * s + 8 * q;
        const bf16x8 bh = ld16B(&Kh[ko]);
        const bf16x8 bm = ld16B(&Km[ko]);
        const bf16x8 bl = ld16B(&Kl[ko]);
        a = MFMA16(ql[s], bh, a);
        a = MFMA16(qh[s], bl, a);
        a = MFMA16(qm[s], bm, a);
        a = MFMA16(qm[s], bh, a);
        a = MFMA16(qh[s], bm, a);
        a = MFMA16(qh[s], bh, a);
      }
      sacc[ct] = a;
    }

    float rmax[4];
    #pragma unroll
    for (int r = 0; r < 4; ++r)
      rmax[r] = fmaxf(sacc[0][r], sacc[1][r]);
    #pragma unroll
    for (int mk = 1; mk <= 8; mk <<= 1) {
      #pragma unroll
      for (int r = 0; r < 4; ++r)
        rmax[r] = fmaxf(rmax[r], __shfl_xor(rmax[r], mk, 64));
    }
    float alpha[4], rsum[4];
    #pragma unroll
    for (int r = 0; r < 4; ++r) {
      const float mnew = fmaxf(m_run[r], rmax[r] * scale);
      alpha[r] = __expf(m_run[r] - mnew);
      m_run[r] = mnew;
      rsum[r] = 0.f;
    }
    #pragma unroll
    for (int ct = 0; ct < 2; ++ct) {
      #pragma unroll
      for (int r = 0; r < 4; ++r) {
        const float pv = __expf(sacc[ct][r] * scale - m_run[r]);
        rsum[r] += pv;
        Pb[(16 * w + 4 * q + r) * 36 + ln + 16 * ct] = pv;
      }
    }
    #pragma unroll
    for (int mk = 1; mk <= 8; mk <<= 1) {
      #pragma unroll
      for (int r = 0; r < 4; ++r)
        rsum[r] += __shfl_xor(rsum[r], mk, 64);
    }
    #pragma unroll
    for (int r = 0; r < 4; ++r)
      l_run[r] = l_run[r] * alpha[r] + rsum[r];

    #pragma unroll
    for (int ct = 0; ct < 4; ++ct) {
      #pragma unroll
      for (int r = 0; r < 4; ++r) O[ct][r] *= alpha[r];
    }

    bf16x8 ph, pm, pl;
    {
      const float* pp = &Pb[(16 * w + ln) * 36 + 8 * q];
      const float4 p0 = ((const float4*)pp)[0];
      const float4 p1 = ((const float4*)pp)[1];
      const float pvv[8] = {p0.x, p0.y, p0.z, p0.w, p1.x, p1.y, p1.z, p1.w};
      union { bf16x8 v; unsigned short e[8]; } uh, um, ul;
      #pragma unroll
      for (int j = 0; j < 8; ++j) {
        unsigned short h, m, l;
        split3(pvv[j], h, m, l);
        uh.e[j] = h; um.e[j] = m; ul.e[j] = l;
      }
      ph = uh.v; pm = um.v; pl = ul.v;
    }

    #pragma unroll
    for (int ct = 0; ct < 4; ++ct) {
      const int vo = (16 * ct + ln) * 40 + 8 * q;
      const bf16x8 vvh = ld16B(&Vh[vo]);
      const bf16x8 vvm = ld16B(&Vm[vo]);
      const bf16x8 vvl = ld16B(&Vl[vo]);
      O[ct] = MFMA16(ph, vvh, O[ct]);
      O[ct] = MFMA16(ph, vvm, O[ct]);
      O[ct] = MFMA16(pm, vvh, O[ct]);
      O[ct] = MFMA16(pm, vvm, O[ct]);
      O[ct] = MFMA16(ph, vvl, O[ct]);
      O[ct] = MFMA16(pl, vvh, O[ct]);
    }
  }

  float linv[4];
  #pragma unroll
  for (int r = 0; r < 4; ++r) linv[r] = 1.0f / l_run[r];
  #pragma unroll
  for (int ct = 0; ct < 4; ++ct) {
    #pragma unroll
    for (int r = 0; r < 4; ++r) {
      float* xp = X + base + (size_t)(i0 + 16 * w + 4 * q + r) * 64 + ln + 16 * ct;
      *xp += O[ct][r] * linv[r];
    }
  }
}

__global__ __launch_bounds__(256) void k_head(
    const float* __restrict__ X, const float* __restrict__ lW,
    const float* __restrict__ lb, float* __restrict__ out) {
  __shared__ float meanv[DIMN];
  __shared__ float red[256];
  const int b    = blockIdx.x;
  const int tid  = threadIdx.x;
  const int lane = tid & 63;
  const int w    = tid >> 6;
  const float* Xb = X + (size_t)b * DIMN * 64;
  for (int n = w; n < DIMN; n += 4) {
    float v = Xb[(size_t)n * 64 + lane];
    #pragma unroll
    for (int off = 32; off > 0; off >>= 1)
      v += __shfl_down(v, off, 64);
    if (lane == 0) meanv[n] = v * (1.0f / 64.0f);
  }
  __syncthreads();
  float acc[NCLS];
  #pragma unroll
  for (int k = 0; k < NCLS; ++k) acc[k] = 0.f;
  for (int n = tid; n < DIMN; n += 256) {
    const float m = meanv[n];
    #pragma unroll
    for (int k = 0; k < NCLS; ++k)
      acc[k] = fmaf(m, lW[k * DIMN + n], acc[k]);
  }
  for (int k = 0; k < NCLS; ++k) {
    red[tid] = acc[k];
    __syncthreads();
    for (int s = 128; s > 0; s >>= 1) {
      if (tid < s) red[tid] += red[tid + s];
      __syncthreads();
    }
    if (tid == 0) out[b * NCLS + k] = red[0] + lb[k];
    __syncthreads();
  }
}

// ---------------------------------------------------------------------------
// launch
// ---------------------------------------------------------------------------
extern "C" void kernel_launch(void* const* d_in, const int* in_sizes, int n_in,
                              void* d_out, int out_size, void* d_ws, size_t ws_size,
                              hipStream_t stream) {
  const float* image = (const float*)d_in[0];
  const float* WV    = (const float*)d_in[1];
  const float* WK    = (const float*)d_in[2];
  const float* WQ    = (const float*)d_in[3];
  const float* lW    = (const float*)d_in[4];
  const float* lb    = (const float*)d_in[5];
  float* out = (float*)d_out;

  float* ws = (float*)d_ws;
  const size_t NELEM = (size_t)BB * DIMN * CCH;   // 2,097,152

  const size_t need_fast = 2 * NELEM * sizeof(float)          // X, Q
                         + 6 * NELEM * sizeof(unsigned short) // K/V splits
                         + (size_t)BB * DIMN * sizeof(float); // meanv

  if (ws_size >= need_fast) {
    float* X = ws;
    float* Q = ws + NELEM;
    unsigned short* Kh  = (unsigned short*)(ws + 2 * NELEM);
    unsigned short* Km  = Kh + NELEM;
    unsigned short* Kl  = Kh + 2 * NELEM;
    unsigned short* VhT = Kh + 3 * NELEM;
    unsigned short* VmT = Kh + 4 * NELEM;
    unsigned short* VlT = Kh + 5 * NELEM;
    float* meanv = (float*)(Kh + 6 * NELEM);

    k_transpose<<<dim3(DIMN / 64, BB), 256, 0, stream>>>(image, X);
    for (int layer = 0; layer < 8; ++layer) {
      k_qkv_split<<<(BB * DIMN) / 16, 256, 0, stream>>>(
          X, WQ, WK, WV, Q, Kh, Km, Kl, VhT, VmT, VlT);
      k_attn_s<<<dim3(DIMN / 64, BB), 256, 0, stream>>>(
          Q, Kh, Km, Kl, VhT, VmT, VlT, X, (layer == 7) ? meanv : nullptr);
    }
    k_head2<<<BB, 256, 0, stream>>>(meanv, lW, lb, out);
  } else {
    float* X = ws;
    float* Q = ws + NELEM;
    float* K = ws + 2 * NELEM;
    float* V = ws + 3 * NELEM;
    k_transpose<<<dim3(DIMN / 64, BB), 256, 0, stream>>>(image, X);
    for (int layer = 0; layer < 8; ++layer) {
      k_qkv<<<(BB * DIMN) / 16, 256, 0, stream>>>(X, WQ, WK, WV, Q, K, V);
      k_attn_mfma<<<dim3(DIMN / 64, BB), 256, 0, stream>>>(Q, K, V, X);
    }
    k_head<<<BB, 256, 0, stream>>>(X, lW, lb, out);
  }
}